// Round 4
// baseline (578.842 us; speedup 1.0000x reference)
//
#include <hip/hip_runtime.h>
#include <hip/hip_bf16.h>

#define NN     14848      // nodes
#define NE     475136     // edges
#define NROI   116        // nodes per graph
#define NGRAPH 128        // graphs
#define EPG    3712       // edges per graph (116*32)
#define HID    64
#define HC     256
#define NEG    0.01f
#define NEGA   0.2f

__device__ __forceinline__ float leaky(float x, float s) { return x >= 0.f ? x : s * x; }

// ---------------------------------------------------------------- embed
__global__ __launch_bounds__(64) void k_embed(
    const float* __restrict__ x, const int* __restrict__ ng,
    const float* __restrict__ gemb, const float* __restrict__ W,
    const float* __restrict__ b, float* __restrict__ h0)
{
    const int n = blockIdx.x, c = threadIdx.x;
    __shared__ float in[132];
    for (int k = c; k < NROI; k += 64) in[k] = x[n * NROI + k];
    if (c < 16) in[NROI + c] = gemb[ng[n] * 16 + c];
    __syncthreads();
    float acc = b[c];
    #pragma unroll 4
    for (int k = 0; k < 132; k++) acc = fmaf(in[k], W[k * 64 + c], acc);
    h0[n * 64 + c] = leaky(acc, NEG);
}

// ---------------------------------------------------------------- CSR build (counting sort by dst, per graph)
__global__ __launch_bounds__(256) void k_csr(
    const int* __restrict__ src, const int* __restrict__ dst,
    const float* __restrict__ ea,
    int* __restrict__ row_start, int* __restrict__ row_cnt,
    int* __restrict__ ssrc, int* __restrict__ sdst, float* __restrict__ ea_s)
{
    const int g = blockIdx.x, tid = threadIdx.x;
    const int e0 = g * EPG, nb = g * NROI;
    __shared__ int cnt[NROI], start[NROI], cur[NROI];
    if (tid < NROI) cnt[tid] = 0;
    __syncthreads();
    for (int i = tid; i < EPG; i += 256) atomicAdd(&cnt[dst[e0 + i] - nb], 1);
    __syncthreads();
    if (tid == 0) {
        int s = 0;
        for (int r = 0; r < NROI; r++) { start[r] = s; s += cnt[r]; }
    }
    __syncthreads();
    if (tid < NROI) {
        row_start[nb + tid] = e0 + start[tid];
        row_cnt[nb + tid] = cnt[tid];
        cur[tid] = start[tid];
    }
    __syncthreads();
    for (int i = tid; i < EPG; i += 256) {
        const int e = e0 + i, dl = dst[e] - nb;
        const int pos = atomicAdd(&cur[dl], 1);
        const int gi = e0 + pos;
        ssrc[gi] = src[e];
        sdst[gi] = dl;
        #pragma unroll
        for (int k = 0; k < 5; k++) ea_s[(size_t)gi * 8 + k] = ea[e * 5 + k];
    }
}

// ---------------------------------------------------------------- GINE (CSR, per-row wave) fused with MLP + LayerNorm
__global__ __launch_bounds__(256) void k_gine_mlp_ln(
    const float* __restrict__ h0, const int* __restrict__ row_start,
    const int* __restrict__ row_cnt, const int* __restrict__ ssrc,
    const float* __restrict__ ea_s,
    const float* __restrict__ We, const float* __restrict__ be,
    const float* __restrict__ W1, const float* __restrict__ b1,
    const float* __restrict__ W2, const float* __restrict__ b2,
    const float* __restrict__ lg_, const float* __restrict__ lb_,
    float* __restrict__ hn)
{
    const int tid = threadIdx.x, w = tid >> 6, lane = tid & 63;
    const int row = blockIdx.x * 4 + w;
    const int st = row_start[row], cnt = row_cnt[row];
    const float w0 = We[lane], w1 = We[64 + lane], w2 = We[128 + lane],
                w3 = We[192 + lane], w4 = We[256 + lane];
    const float bec = be[lane];
    float g0 = 0.f, g1 = 0.f;
    int j = 0;
    for (; j + 2 <= cnt; j += 2) {
        const int ia = st + j, ib = st + j + 1;
        const int sa = ssrc[ia], sb = ssrc[ib];
        const float4 qa = *(const float4*)&ea_s[(size_t)ia * 8];
        const float qa4 = ea_s[(size_t)ia * 8 + 4];
        const float4 qb = *(const float4*)&ea_s[(size_t)ib * 8];
        const float qb4 = ea_s[(size_t)ib * 8 + 4];
        float ea_ = bec, eb_ = bec;
        ea_ = fmaf(qa.x, w0, ea_); eb_ = fmaf(qb.x, w0, eb_);
        ea_ = fmaf(qa.y, w1, ea_); eb_ = fmaf(qb.y, w1, eb_);
        ea_ = fmaf(qa.z, w2, ea_); eb_ = fmaf(qb.z, w2, eb_);
        ea_ = fmaf(qa.w, w3, ea_); eb_ = fmaf(qb.w, w3, eb_);
        ea_ = fmaf(qa4, w4, ea_);  eb_ = fmaf(qb4, w4, eb_);
        g0 += fmaxf(h0[sa * 64 + lane] + leaky(ea_, NEG), 0.f);
        g1 += fmaxf(h0[sb * 64 + lane] + leaky(eb_, NEG), 0.f);
    }
    for (; j < cnt; j++) {
        const int idx = st + j;
        const int s = ssrc[idx];
        const float4 q = *(const float4*)&ea_s[(size_t)idx * 8];
        const float q4 = ea_s[(size_t)idx * 8 + 4];
        float em = bec;
        em = fmaf(q.x, w0, em); em = fmaf(q.y, w1, em); em = fmaf(q.z, w2, em);
        em = fmaf(q.w, w3, em); em = fmaf(q4, w4, em);
        g0 += fmaxf(h0[s * 64 + lane] + leaky(em, NEG), 0.f);
    }
    const float aggv = g0 + g1;
    __shared__ float v[4][64], t[4][64];
    v[w][lane] = h0[row * 64 + lane] + aggv;
    __syncthreads();
    float a = b1[lane];
    #pragma unroll 8
    for (int k = 0; k < 64; k++) a = fmaf(v[w][k], W1[k * 64 + lane], a);
    t[w][lane] = leaky(a, NEG);
    __syncthreads();
    float o = b2[lane];
    #pragma unroll 8
    for (int k = 0; k < 64; k++) o = fmaf(t[w][k], W2[k * 64 + lane], o);
    o = leaky(o, NEG);
    float s = o;
    #pragma unroll
    for (int off = 32; off; off >>= 1) s += __shfl_xor(s, off);
    const float mu = s * (1.f / 64.f);
    const float d = o - mu;
    float s2 = d * d;
    #pragma unroll
    for (int off = 32; off; off >>= 1) s2 += __shfl_xor(s2, off);
    hn[row * 64 + lane] = d * rsqrtf(s2 * (1.f / 64.f) + 1e-5f) * lg_[lane] + lb_[lane];
}

// ---------------------------------------------------------------- xl/xr projections (optionally fused BN+leaky on load)
// NOTE: BN path assumes D==256 (each thread loads exactly channel c).
template <int D, bool BN>
__global__ __launch_bounds__(256) void k_xlxr(
    const float* __restrict__ hin, const float* __restrict__ stats,
    const float* __restrict__ bn_g, const float* __restrict__ bn_b,
    const float* __restrict__ Wl, const float* __restrict__ Wr,
    float* __restrict__ X, float* __restrict__ Y)
{
    const int c = threadIdx.x;
    const int n0 = blockIdx.x * 16;
    float mu = 0.f, rsg = 0.f, bb = 0.f;
    if constexpr (BN) {
        const float inv_n = 1.f / (float)NN;
        mu = stats[c] * inv_n;
        float var = stats[256 + c] * inv_n - mu * mu;
        var = fmaxf(var, 0.f);
        rsg = rsqrtf(var + 1e-5f) * bn_g[c];
        bb = bn_b[c];
    }
    __shared__ float v[16][D];
    #pragma unroll
    for (int j = 0; j < 16; j++)
        for (int k = c; k < D; k += 256) {
            float hv = hin[(size_t)(n0 + j) * D + k];
            if constexpr (BN) hv = leaky((hv - mu) * rsg + bb, NEG);
            v[j][k] = hv;
        }
    __syncthreads();
    float aL[16], aR[16];
    #pragma unroll
    for (int j = 0; j < 16; j++) { aL[j] = 0.f; aR[j] = 0.f; }
    for (int k = 0; k < D; k++) {
        const float wl = Wl[k * HC + c], wr = Wr[k * HC + c];
        #pragma unroll
        for (int j = 0; j < 16; j++) {
            const float hv = v[j][k];
            aL[j] = fmaf(hv, wl, aL[j]);
            aR[j] = fmaf(hv, wr, aR[j]);
        }
    }
    #pragma unroll
    for (int j = 0; j < 16; j++) {
        X[(size_t)(n0 + j) * HC + c] = aL[j];
        Y[(size_t)(n0 + j) * HC + c] = aR[j];
    }
}

// ---------------------------------------------------------------- fused GATv2: one block per (graph, head), 512 threads
// phase A: lane=edge logits (4-acc ILP, float4 Y); B: per-row softmax; C: numerator + BN stat partials
__global__ __launch_bounds__(512, 2) void k_gat(
    const int* __restrict__ row_start, const int* __restrict__ row_cnt,
    const int* __restrict__ ssrc, const int* __restrict__ sdst,
    const float* __restrict__ ea_s,
    const float* __restrict__ We, const float* __restrict__ att,
    const float* __restrict__ bias,
    const float* __restrict__ X, const float* __restrict__ Y,
    float* __restrict__ V, float* __restrict__ stats)
{
    const int g = blockIdx.x >> 2, h = blockIdx.x & 3;
    const int tid = threadIdx.x, w = tid >> 6, lane = tid & 63;
    const int nb = g * NROI, e0 = g * EPG, hc = h * 64;

    __shared__ float Xs[NROI * 65];   // pad 65: odd stride -> random rows spread banks
    __shared__ float lg[EPG];

    for (int r = w; r < NROI; r += 8)
        Xs[r * 65 + lane] = X[(size_t)(nb + r) * HC + hc + lane];
    __syncthreads();

    // ---- phase A: logits, lane = edge
    for (int i = tid; i < EPG; i += 512) {
        const int e = e0 + i;
        const int sl = ssrc[e] - nb;
        const int dl = sdst[e];
        const float4 q = *(const float4*)&ea_s[(size_t)e * 8];
        const float q4 = ea_s[(size_t)e * 8 + 4];
        const float* yrow = &Y[(size_t)(nb + dl) * HC + hc];
        const float* xrow = &Xs[sl * 65];
        float a0 = 0.f, a1 = 0.f, a2 = 0.f, a3 = 0.f;
        #pragma unroll
        for (int c = 0; c < 64; c += 4) {
            const float4 y4 = *(const float4*)(yrow + c);
            float e0_ = q.x * We[0 * HC + hc + c + 0];
            e0_ = fmaf(q.y, We[1 * HC + hc + c + 0], e0_);
            e0_ = fmaf(q.z, We[2 * HC + hc + c + 0], e0_);
            e0_ = fmaf(q.w, We[3 * HC + hc + c + 0], e0_);
            e0_ = fmaf(q4, We[4 * HC + hc + c + 0], e0_);
            float e1_ = q.x * We[0 * HC + hc + c + 1];
            e1_ = fmaf(q.y, We[1 * HC + hc + c + 1], e1_);
            e1_ = fmaf(q.z, We[2 * HC + hc + c + 1], e1_);
            e1_ = fmaf(q.w, We[3 * HC + hc + c + 1], e1_);
            e1_ = fmaf(q4, We[4 * HC + hc + c + 1], e1_);
            float e2_ = q.x * We[0 * HC + hc + c + 2];
            e2_ = fmaf(q.y, We[1 * HC + hc + c + 2], e2_);
            e2_ = fmaf(q.z, We[2 * HC + hc + c + 2], e2_);
            e2_ = fmaf(q.w, We[3 * HC + hc + c + 2], e2_);
            e2_ = fmaf(q4, We[4 * HC + hc + c + 2], e2_);
            float e3_ = q.x * We[0 * HC + hc + c + 3];
            e3_ = fmaf(q.y, We[1 * HC + hc + c + 3], e3_);
            e3_ = fmaf(q.z, We[2 * HC + hc + c + 3], e3_);
            e3_ = fmaf(q.w, We[3 * HC + hc + c + 3], e3_);
            e3_ = fmaf(q4, We[4 * HC + hc + c + 3], e3_);
            const float z0 = xrow[c + 0] + y4.x + e0_;
            const float z1 = xrow[c + 1] + y4.y + e1_;
            const float z2 = xrow[c + 2] + y4.z + e2_;
            const float z3 = xrow[c + 3] + y4.w + e3_;
            a0 = fmaf(att[hc + c + 0], leaky(z0, NEGA), a0);
            a1 = fmaf(att[hc + c + 1], leaky(z1, NEGA), a1);
            a2 = fmaf(att[hc + c + 2], leaky(z2, NEGA), a2);
            a3 = fmaf(att[hc + c + 3], leaky(z3, NEGA), a3);
        }
        lg[i] = (a0 + a1) + (a2 + a3);
    }
    __syncthreads();

    // ---- phase B: per-row softmax (wave per row, lanes = edges)
    for (int r = w; r < NROI; r += 8) {
        const int stl = row_start[nb + r] - e0;
        const int cnt = row_cnt[nb + r];
        float m = -INFINITY;
        for (int j = lane; j < cnt; j += 64) m = fmaxf(m, lg[stl + j]);
        #pragma unroll
        for (int off = 32; off; off >>= 1) m = fmaxf(m, __shfl_xor(m, off));
        float s = 0.f;
        for (int j = lane; j < cnt; j += 64) {
            const float e_ = __expf(lg[stl + j] - m);
            lg[stl + j] = e_;
            s += e_;
        }
        #pragma unroll
        for (int off = 32; off; off >>= 1) s += __shfl_xor(s, off);
        const float inv = 1.f / (s + 1e-16f);
        for (int j = lane; j < cnt; j += 64) lg[stl + j] *= inv;
    }
    __syncthreads();

    // ---- phase C: numerator (wave per row, lane = channel) + BN partials
    float ps = 0.f, ps2 = 0.f;
    const float bb = bias[hc + lane];
    for (int r = w; r < NROI; r += 8) {
        const int st = row_start[nb + r];
        const int cnt = row_cnt[nb + r];
        const int stl = st - e0;
        float a0 = 0.f, a1 = 0.f, a2 = 0.f, a3 = 0.f;
        int j = 0;
        for (; j + 4 <= cnt; j += 4) {
            const int s0 = ssrc[st + j] - nb, s1 = ssrc[st + j + 1] - nb,
                      s2 = ssrc[st + j + 2] - nb, s3 = ssrc[st + j + 3] - nb;
            a0 = fmaf(Xs[s0 * 65 + lane], lg[stl + j], a0);
            a1 = fmaf(Xs[s1 * 65 + lane], lg[stl + j + 1], a1);
            a2 = fmaf(Xs[s2 * 65 + lane], lg[stl + j + 2], a2);
            a3 = fmaf(Xs[s3 * 65 + lane], lg[stl + j + 3], a3);
        }
        for (; j < cnt; j++)
            a0 = fmaf(Xs[(ssrc[st + j] - nb) * 65 + lane], lg[stl + j], a0);
        const float vv = (a0 + a1) + (a2 + a3) + bb;
        V[(size_t)(nb + r) * HC + hc + lane] = vv;
        ps += vv;
        ps2 += vv * vv;
    }
    __syncthreads();                 // lg free now; reuse as reduction buffer
    lg[tid] = ps;
    lg[512 + tid] = ps2;
    __syncthreads();
    if (tid < 64) {
        float s1 = 0.f, s2 = 0.f;
        #pragma unroll
        for (int w2 = 0; w2 < 8; w2++) {
            s1 += lg[w2 * 64 + tid];
            s2 += lg[512 + w2 * 64 + tid];
        }
        atomicAdd(&stats[hc + tid], s1);
        atomicAdd(&stats[256 + hc + tid], s2);
    }
}

// ---------------------------------------------------------------- BN + leaky + mean-pool + classifier
__global__ __launch_bounds__(256) void k_pool_fc(
    const float* __restrict__ V, const float* __restrict__ stats,
    const float* __restrict__ bg, const float* __restrict__ bb,
    const float* __restrict__ fW, const float* __restrict__ fb,
    float* __restrict__ out)
{
    const int g = blockIdx.x, c = threadIdx.x;
    const float inv_n = 1.f / (float)NN;
    const float mu = stats[c] * inv_n;
    float var = stats[256 + c] * inv_n - mu * mu;
    var = fmaxf(var, 0.f);
    const float rsg = rsqrtf(var + 1e-5f) * bg[c];
    const float bbc = bb[c];
    float s = 0.f;
    for (int r = 0; r < NROI; r++) {
        const float vv = (V[(size_t)(g * NROI + r) * HC + c] - mu) * rsg + bbc;
        s += leaky(vv, NEG);
    }
    s *= (1.f / (float)NROI);
    __shared__ float red[256];
    for (int o = 0; o < 2; o++) {
        red[c] = s * fW[c * 2 + o];
        __syncthreads();
        for (int off = 128; off; off >>= 1) {
            if (c < off) red[c] += red[c + off];
            __syncthreads();
        }
        if (c == 0) out[g * 2 + o] = red[0] + fb[o];
        __syncthreads();
    }
}

extern "C" void kernel_launch(void* const* d_in, const int* in_sizes, int n_in,
                              void* d_out, int out_size, void* d_ws, size_t ws_size,
                              hipStream_t stream) {
    const float* x         = (const float*)d_in[0];
    const int*   edge_idx  = (const int*)d_in[1];
    const float* edge_attr = (const float*)d_in[2];
    const int*   node_grp  = (const int*)d_in[4];
    const float* group_emb = (const float*)d_in[5];
    const float* W_embed   = (const float*)d_in[6];
    const float* b_embed   = (const float*)d_in[7];
    const float* We_enc    = (const float*)d_in[8];
    const float* be_enc    = (const float*)d_in[9];
    const float* W1        = (const float*)d_in[10];
    const float* b1        = (const float*)d_in[11];
    const float* W2        = (const float*)d_in[12];
    const float* b2        = (const float*)d_in[13];
    const float* ln_g      = (const float*)d_in[14];
    const float* ln_b      = (const float*)d_in[15];
    const float* l0_Wl     = (const float*)d_in[16];
    const float* l0_Wr     = (const float*)d_in[17];
    const float* l0_We     = (const float*)d_in[18];
    const float* l0_att    = (const float*)d_in[19];
    const float* l0_b      = (const float*)d_in[20];
    const float* l0_bn_g   = (const float*)d_in[21];
    const float* l0_bn_b   = (const float*)d_in[22];
    const float* l1_Wl     = (const float*)d_in[23];
    const float* l1_Wr     = (const float*)d_in[24];
    const float* l1_We     = (const float*)d_in[25];
    const float* l1_att    = (const float*)d_in[26];
    const float* l1_b      = (const float*)d_in[27];
    const float* l1_bn_g   = (const float*)d_in[28];
    const float* l1_bn_b   = (const float*)d_in[29];
    const float* fc2_W     = (const float*)d_in[30];
    const float* fc2_b     = (const float*)d_in[31];

    const int* src = edge_idx;
    const int* dst = edge_idx + NE;

    float* ws     = (float*)d_ws;
    float* h0     = ws;                       // 64*NN
    float* hn     = h0 + (size_t)64 * NN;     // 64*NN
    float* X      = hn + (size_t)64 * NN;     // 256*NN
    float* Y      = X + (size_t)HC * NN;      // 256*NN
    float* V      = Y + (size_t)HC * NN;      // 256*NN
    float* stats0 = V + (size_t)HC * NN;      // 512
    float* stats1 = stats0 + 512;             // 512
    float* ea_s   = stats1 + 512;             // 8*NE
    int* row_start = (int*)(ea_s + (size_t)8 * NE);  // NN
    int* row_cnt   = row_start + NN;                 // NN
    int* ssrc      = row_cnt + NN;                   // NE
    int* sdst      = ssrc + NE;                      // NE

    float* out = (float*)d_out;

    hipMemsetAsync(stats0, 0, 1024 * sizeof(float), stream);  // stats0 + stats1
    k_embed<<<NN, 64, 0, stream>>>(x, node_grp, group_emb, W_embed, b_embed, h0);
    k_csr<<<NGRAPH, 256, 0, stream>>>(src, dst, edge_attr, row_start, row_cnt, ssrc, sdst, ea_s);
    k_gine_mlp_ln<<<NN / 4, 256, 0, stream>>>(h0, row_start, row_cnt, ssrc, ea_s,
                                              We_enc, be_enc, W1, b1, W2, b2, ln_g, ln_b, hn);

    // GAT layer 0
    k_xlxr<64, false><<<NN / 16, 256, 0, stream>>>(hn, nullptr, nullptr, nullptr,
                                                   l0_Wl, l0_Wr, X, Y);
    k_gat<<<NGRAPH * 4, 512, 0, stream>>>(row_start, row_cnt, ssrc, sdst, ea_s,
                                          l0_We, l0_att, l0_b, X, Y, V, stats0);

    // GAT layer 1 (BN+leaky of layer-0 output fused into projection load)
    k_xlxr<256, true><<<NN / 16, 256, 0, stream>>>(V, stats0, l0_bn_g, l0_bn_b,
                                                   l1_Wl, l1_Wr, X, Y);
    k_gat<<<NGRAPH * 4, 512, 0, stream>>>(row_start, row_cnt, ssrc, sdst, ea_s,
                                          l1_We, l1_att, l1_b, X, Y, V, stats1);

    // BN+leaky of layer-1 output fused into pooling
    k_pool_fc<<<NGRAPH, 256, 0, stream>>>(V, stats1, l1_bn_g, l1_bn_b, fc2_W, fc2_b, out);
}

// Round 5
// 505.910 us; speedup vs baseline: 1.1442x; 1.1442x over previous
//
#include <hip/hip_runtime.h>
#include <hip/hip_bf16.h>

#define NN     14848      // nodes
#define NE     475136     // edges
#define NROI   116        // nodes per graph
#define NGRAPH 128        // graphs
#define EPG    3712       // edges per graph (116*32)
#define HID    64
#define HC     256
#define NEG    0.01f
#define NEGA   0.2f
#define EPB    2304       // max edges per half-graph block (mean 1856)

__device__ __forceinline__ float leaky(float x, float s) { return x >= 0.f ? x : s * x; }

// ---------------------------------------------------------------- embed
__global__ __launch_bounds__(64) void k_embed(
    const float* __restrict__ x, const int* __restrict__ ng,
    const float* __restrict__ gemb, const float* __restrict__ W,
    const float* __restrict__ b, float* __restrict__ h0)
{
    const int n = blockIdx.x, c = threadIdx.x;
    __shared__ float in[132];
    for (int k = c; k < NROI; k += 64) in[k] = x[n * NROI + k];
    if (c < 16) in[NROI + c] = gemb[ng[n] * 16 + c];
    __syncthreads();
    float acc = b[c];
    #pragma unroll 4
    for (int k = 0; k < 132; k++) acc = fmaf(in[k], W[k * 64 + c], acc);
    h0[n * 64 + c] = leaky(acc, NEG);
}

// ---------------------------------------------------------------- CSR build (counting sort by dst, per graph)
// ssd[gi] = (local src) | (local dst << 16); ea_s stride-8 (float4 + float)
__global__ __launch_bounds__(256) void k_csr(
    const int* __restrict__ src, const int* __restrict__ dst,
    const float* __restrict__ ea,
    int* __restrict__ row_start, int* __restrict__ row_cnt,
    int* __restrict__ ssd, float* __restrict__ ea_s)
{
    const int g = blockIdx.x, tid = threadIdx.x;
    const int e0 = g * EPG, nb = g * NROI;
    __shared__ int cnt[NROI], start[NROI], cur[NROI];
    if (tid < NROI) cnt[tid] = 0;
    __syncthreads();
    for (int i = tid; i < EPG; i += 256) atomicAdd(&cnt[dst[e0 + i] - nb], 1);
    __syncthreads();
    if (tid == 0) {
        int s = 0;
        for (int r = 0; r < NROI; r++) { start[r] = s; s += cnt[r]; }
    }
    __syncthreads();
    if (tid < NROI) {
        row_start[nb + tid] = e0 + start[tid];
        row_cnt[nb + tid] = cnt[tid];
        cur[tid] = start[tid];
    }
    __syncthreads();
    for (int i = tid; i < EPG; i += 256) {
        const int e = e0 + i, dl = dst[e] - nb;
        const int pos = atomicAdd(&cur[dl], 1);
        const int gi = e0 + pos;
        ssd[gi] = (src[e] - nb) | (dl << 16);
        const float4 q = make_float4(ea[e * 5], ea[e * 5 + 1], ea[e * 5 + 2], ea[e * 5 + 3]);
        *(float4*)&ea_s[(size_t)gi * 8] = q;
        ea_s[(size_t)gi * 8 + 4] = ea[e * 5 + 4];
    }
}

// ---------------------------------------------------------------- GINE (CSR, per-row wave) fused with MLP + LayerNorm
__global__ __launch_bounds__(256) void k_gine_mlp_ln(
    const float* __restrict__ h0, const int* __restrict__ row_start,
    const int* __restrict__ row_cnt, const int* __restrict__ ssd,
    const float* __restrict__ ea_s,
    const float* __restrict__ We, const float* __restrict__ be,
    const float* __restrict__ W1, const float* __restrict__ b1,
    const float* __restrict__ W2, const float* __restrict__ b2,
    const float* __restrict__ lg_, const float* __restrict__ lb_,
    float* __restrict__ hn)
{
    const int tid = threadIdx.x, w = tid >> 6, lane = tid & 63;
    const int row = blockIdx.x * 4 + w;
    const int nb = (row / NROI) * NROI;
    const int st = row_start[row], cnt = row_cnt[row];
    const float w0 = We[lane], w1 = We[64 + lane], w2 = We[128 + lane],
                w3 = We[192 + lane], w4 = We[256 + lane];
    const float bec = be[lane];
    float g0 = 0.f, g1 = 0.f;
    int j = 0;
    for (; j + 2 <= cnt; j += 2) {
        const int ia = st + j, ib = st + j + 1;
        const int sa = nb + (ssd[ia] & 0xffff), sb = nb + (ssd[ib] & 0xffff);
        const float4 qa = *(const float4*)&ea_s[(size_t)ia * 8];
        const float qa4 = ea_s[(size_t)ia * 8 + 4];
        const float4 qb = *(const float4*)&ea_s[(size_t)ib * 8];
        const float qb4 = ea_s[(size_t)ib * 8 + 4];
        float ea_ = bec, eb_ = bec;
        ea_ = fmaf(qa.x, w0, ea_); eb_ = fmaf(qb.x, w0, eb_);
        ea_ = fmaf(qa.y, w1, ea_); eb_ = fmaf(qb.y, w1, eb_);
        ea_ = fmaf(qa.z, w2, ea_); eb_ = fmaf(qb.z, w2, eb_);
        ea_ = fmaf(qa.w, w3, ea_); eb_ = fmaf(qb.w, w3, eb_);
        ea_ = fmaf(qa4, w4, ea_);  eb_ = fmaf(qb4, w4, eb_);
        g0 += fmaxf(h0[sa * 64 + lane] + leaky(ea_, NEG), 0.f);
        g1 += fmaxf(h0[sb * 64 + lane] + leaky(eb_, NEG), 0.f);
    }
    for (; j < cnt; j++) {
        const int idx = st + j;
        const int s = nb + (ssd[idx] & 0xffff);
        const float4 q = *(const float4*)&ea_s[(size_t)idx * 8];
        const float q4 = ea_s[(size_t)idx * 8 + 4];
        float em = bec;
        em = fmaf(q.x, w0, em); em = fmaf(q.y, w1, em); em = fmaf(q.z, w2, em);
        em = fmaf(q.w, w3, em); em = fmaf(q4, w4, em);
        g0 += fmaxf(h0[s * 64 + lane] + leaky(em, NEG), 0.f);
    }
    const float aggv = g0 + g1;
    __shared__ float v[4][64], t[4][64];
    v[w][lane] = h0[row * 64 + lane] + aggv;
    __syncthreads();
    float a = b1[lane];
    #pragma unroll 8
    for (int k = 0; k < 64; k++) a = fmaf(v[w][k], W1[k * 64 + lane], a);
    t[w][lane] = leaky(a, NEG);
    __syncthreads();
    float o = b2[lane];
    #pragma unroll 8
    for (int k = 0; k < 64; k++) o = fmaf(t[w][k], W2[k * 64 + lane], o);
    o = leaky(o, NEG);
    float s = o;
    #pragma unroll
    for (int off = 32; off; off >>= 1) s += __shfl_xor(s, off);
    const float mu = s * (1.f / 64.f);
    const float d = o - mu;
    float s2 = d * d;
    #pragma unroll
    for (int off = 32; off; off >>= 1) s2 += __shfl_xor(s2, off);
    hn[row * 64 + lane] = d * rsqrtf(s2 * (1.f / 64.f) + 1e-5f) * lg_[lane] + lb_[lane];
}

// ---------------------------------------------------------------- xl/xr projections (optionally fused BN+leaky on load)
template <int D, bool BN>
__global__ __launch_bounds__(256) void k_xlxr(
    const float* __restrict__ hin, const float* __restrict__ stats,
    const float* __restrict__ bn_g, const float* __restrict__ bn_b,
    const float* __restrict__ Wl, const float* __restrict__ Wr,
    float* __restrict__ X, float* __restrict__ Y)
{
    const int c = threadIdx.x;
    const int n0 = blockIdx.x * 16;
    float mu = 0.f, rsg = 0.f, bb = 0.f;
    if constexpr (BN) {
        const float inv_n = 1.f / (float)NN;
        mu = stats[c] * inv_n;
        float var = stats[256 + c] * inv_n - mu * mu;
        var = fmaxf(var, 0.f);
        rsg = rsqrtf(var + 1e-5f) * bn_g[c];
        bb = bn_b[c];
    }
    __shared__ float v[16][D];
    #pragma unroll
    for (int j = 0; j < 16; j++)
        for (int k = c; k < D; k += 256) {
            float hv = hin[(size_t)(n0 + j) * D + k];
            if constexpr (BN) hv = leaky((hv - mu) * rsg + bb, NEG);
            v[j][k] = hv;
        }
    __syncthreads();
    float aL[16], aR[16];
    #pragma unroll
    for (int j = 0; j < 16; j++) { aL[j] = 0.f; aR[j] = 0.f; }
    for (int k = 0; k < D; k++) {
        const float wl = Wl[k * HC + c], wr = Wr[k * HC + c];
        #pragma unroll
        for (int j = 0; j < 16; j++) {
            const float hv = v[j][k];
            aL[j] = fmaf(hv, wl, aL[j]);
            aR[j] = fmaf(hv, wr, aR[j]);
        }
    }
    #pragma unroll
    for (int j = 0; j < 16; j++) {
        X[(size_t)(n0 + j) * HC + c] = aL[j];
        Y[(size_t)(n0 + j) * HC + c] = aR[j];
    }
}

// ---------------------------------------------------------------- fused GATv2 (R3 shape): block = (graph, head, half)
// A: lane=edge logits (scalar Y, unroll-8); B: per-row max/exp/sum -> inv; C: numerator*inv + BN partials
__global__ __launch_bounds__(256, 4) void k_gat(
    const int* __restrict__ row_start, const int* __restrict__ row_cnt,
    const int* __restrict__ ssd, const float* __restrict__ ea_s,
    const float* __restrict__ We, const float* __restrict__ att,
    const float* __restrict__ bias,
    const float* __restrict__ X, const float* __restrict__ Y,
    float* __restrict__ V, float* __restrict__ stats)
{
    const int g = blockIdx.x >> 3;
    const int h = (blockIdx.x >> 1) & 3;
    const int half = blockIdx.x & 1;
    const int tid = threadIdx.x, w = tid >> 6, lane = tid & 63;
    const int nb = g * NROI, e0 = g * EPG, hc = h * 64;
    const int r0 = half * 58, r1 = r0 + 58;
    const int es = row_start[nb + r0];
    const int ee = (r1 < NROI) ? row_start[nb + r1] : e0 + EPG;

    __shared__ float Xs[NROI * 65];   // pad 65: odd stride spreads banks
    __shared__ float lg[EPB];
    __shared__ float inv_s[58];

    for (int r = w; r < NROI; r += 4)
        Xs[r * 65 + lane] = X[(size_t)(nb + r) * HC + hc + lane];
    __syncthreads();

    // ---- phase A: logits, lane = edge (R3-proven inner loop)
    const int ne = ee - es;
    for (int i = tid; i < ne; i += 256) {
        const int e = es + i;
        const int sd = ssd[e];
        const int sl = sd & 0xffff, dl = sd >> 16;
        const float4 q = *(const float4*)&ea_s[(size_t)e * 8];
        const float q4 = ea_s[(size_t)e * 8 + 4];
        const float* yrow = &Y[(size_t)(nb + dl) * HC + hc];
        const int xb = sl * 65;
        float lacc = 0.f;
        #pragma unroll 8
        for (int c = 0; c < 64; c++) {
            float ep = q.x * We[0 * HC + hc + c];
            ep = fmaf(q.y, We[1 * HC + hc + c], ep);
            ep = fmaf(q.z, We[2 * HC + hc + c], ep);
            ep = fmaf(q.w, We[3 * HC + hc + c], ep);
            ep = fmaf(q4, We[4 * HC + hc + c], ep);
            const float z = Xs[xb + c] + yrow[c] + ep;
            lacc = fmaf(att[hc + c], leaky(z, NEGA), lacc);
        }
        lg[i] = lacc;
    }
    __syncthreads();

    // ---- phase B: per-row max / exp / sum; store reciprocal (no normalize pass)
    for (int r = r0 + w; r < r1; r += 4) {
        const int stl = row_start[nb + r] - es;
        const int cnt = row_cnt[nb + r];
        float m = -INFINITY;
        for (int j = lane; j < cnt; j += 64) m = fmaxf(m, lg[stl + j]);
        #pragma unroll
        for (int off = 32; off; off >>= 1) m = fmaxf(m, __shfl_xor(m, off));
        float s = 0.f;
        for (int j = lane; j < cnt; j += 64) {
            const float e_ = __expf(lg[stl + j] - m);
            lg[stl + j] = e_;
            s += e_;
        }
        #pragma unroll
        for (int off = 32; off; off >>= 1) s += __shfl_xor(s, off);
        if (lane == 0) inv_s[r - r0] = 1.f / (s + 1e-16f);
    }
    __syncthreads();

    // ---- phase C: numerator (wave per row, lane = channel) + BN partials
    float ps = 0.f, ps2 = 0.f;
    const float bb = bias[hc + lane];
    for (int r = r0 + w; r < r1; r += 4) {
        const int st = row_start[nb + r];
        const int cnt = row_cnt[nb + r];
        const int stl = st - es;
        float a0 = 0.f, a1 = 0.f, a2 = 0.f, a3 = 0.f;
        int j = 0;
        for (; j + 4 <= cnt; j += 4) {
            const int s0 = ssd[st + j] & 0xffff, s1 = ssd[st + j + 1] & 0xffff,
                      s2 = ssd[st + j + 2] & 0xffff, s3 = ssd[st + j + 3] & 0xffff;
            a0 = fmaf(Xs[s0 * 65 + lane], lg[stl + j], a0);
            a1 = fmaf(Xs[s1 * 65 + lane], lg[stl + j + 1], a1);
            a2 = fmaf(Xs[s2 * 65 + lane], lg[stl + j + 2], a2);
            a3 = fmaf(Xs[s3 * 65 + lane], lg[stl + j + 3], a3);
        }
        for (; j < cnt; j++)
            a0 = fmaf(Xs[(ssd[st + j] & 0xffff) * 65 + lane], lg[stl + j], a0);
        const float vv = ((a0 + a1) + (a2 + a3)) * inv_s[r - r0] + bb;
        V[(size_t)(nb + r) * HC + hc + lane] = vv;
        ps += vv;
        ps2 += vv * vv;
    }
    __syncthreads();                 // lg free; reuse as reduction buffer
    lg[tid] = ps;
    lg[256 + tid] = ps2;
    __syncthreads();
    if (tid < 64) {
        float s1 = 0.f, s2 = 0.f;
        #pragma unroll
        for (int w2 = 0; w2 < 4; w2++) {
            s1 += lg[w2 * 64 + tid];
            s2 += lg[256 + w2 * 64 + tid];
        }
        atomicAdd(&stats[hc + tid], s1);
        atomicAdd(&stats[256 + hc + tid], s2);
    }
}

// ---------------------------------------------------------------- BN + leaky + mean-pool + classifier
__global__ __launch_bounds__(256) void k_pool_fc(
    const float* __restrict__ V, const float* __restrict__ stats,
    const float* __restrict__ bg, const float* __restrict__ bb,
    const float* __restrict__ fW, const float* __restrict__ fb,
    float* __restrict__ out)
{
    const int g = blockIdx.x, c = threadIdx.x;
    const float inv_n = 1.f / (float)NN;
    const float mu = stats[c] * inv_n;
    float var = stats[256 + c] * inv_n - mu * mu;
    var = fmaxf(var, 0.f);
    const float rsg = rsqrtf(var + 1e-5f) * bg[c];
    const float bbc = bb[c];
    float s = 0.f;
    for (int r = 0; r < NROI; r++) {
        const float vv = (V[(size_t)(g * NROI + r) * HC + c] - mu) * rsg + bbc;
        s += leaky(vv, NEG);
    }
    s *= (1.f / (float)NROI);
    __shared__ float red[256];
    for (int o = 0; o < 2; o++) {
        red[c] = s * fW[c * 2 + o];
        __syncthreads();
        for (int off = 128; off; off >>= 1) {
            if (c < off) red[c] += red[c + off];
            __syncthreads();
        }
        if (c == 0) out[g * 2 + o] = red[0] + fb[o];
        __syncthreads();
    }
}

extern "C" void kernel_launch(void* const* d_in, const int* in_sizes, int n_in,
                              void* d_out, int out_size, void* d_ws, size_t ws_size,
                              hipStream_t stream) {
    const float* x         = (const float*)d_in[0];
    const int*   edge_idx  = (const int*)d_in[1];
    const float* edge_attr = (const float*)d_in[2];
    const int*   node_grp  = (const int*)d_in[4];
    const float* group_emb = (const float*)d_in[5];
    const float* W_embed   = (const float*)d_in[6];
    const float* b_embed   = (const float*)d_in[7];
    const float* We_enc    = (const float*)d_in[8];
    const float* be_enc    = (const float*)d_in[9];
    const float* W1        = (const float*)d_in[10];
    const float* b1        = (const float*)d_in[11];
    const float* W2        = (const float*)d_in[12];
    const float* b2        = (const float*)d_in[13];
    const float* ln_g      = (const float*)d_in[14];
    const float* ln_b      = (const float*)d_in[15];
    const float* l0_Wl     = (const float*)d_in[16];
    const float* l0_Wr     = (const float*)d_in[17];
    const float* l0_We     = (const float*)d_in[18];
    const float* l0_att    = (const float*)d_in[19];
    const float* l0_b      = (const float*)d_in[20];
    const float* l0_bn_g   = (const float*)d_in[21];
    const float* l0_bn_b   = (const float*)d_in[22];
    const float* l1_Wl     = (const float*)d_in[23];
    const float* l1_Wr     = (const float*)d_in[24];
    const float* l1_We     = (const float*)d_in[25];
    const float* l1_att    = (const float*)d_in[26];
    const float* l1_b      = (const float*)d_in[27];
    const float* l1_bn_g   = (const float*)d_in[28];
    const float* l1_bn_b   = (const float*)d_in[29];
    const float* fc2_W     = (const float*)d_in[30];
    const float* fc2_b     = (const float*)d_in[31];

    const int* src = edge_idx;
    const int* dst = edge_idx + NE;

    float* ws     = (float*)d_ws;
    float* h0     = ws;                       // 64*NN
    float* hn     = h0 + (size_t)64 * NN;     // 64*NN
    float* X      = hn + (size_t)64 * NN;     // 256*NN
    float* Y      = X + (size_t)HC * NN;      // 256*NN
    float* V      = Y + (size_t)HC * NN;      // 256*NN
    float* stats0 = V + (size_t)HC * NN;      // 512
    float* stats1 = stats0 + 512;             // 512
    float* ea_s   = stats1 + 512;             // 8*NE
    int* row_start = (int*)(ea_s + (size_t)8 * NE);  // NN
    int* row_cnt   = row_start + NN;                 // NN
    int* ssd       = row_cnt + NN;                   // NE

    float* out = (float*)d_out;

    hipMemsetAsync(stats0, 0, 1024 * sizeof(float), stream);  // stats0 + stats1
    k_embed<<<NN, 64, 0, stream>>>(x, node_grp, group_emb, W_embed, b_embed, h0);
    k_csr<<<NGRAPH, 256, 0, stream>>>(src, dst, edge_attr, row_start, row_cnt, ssd, ea_s);
    k_gine_mlp_ln<<<NN / 4, 256, 0, stream>>>(h0, row_start, row_cnt, ssd, ea_s,
                                              We_enc, be_enc, W1, b1, W2, b2, ln_g, ln_b, hn);

    // GAT layer 0
    k_xlxr<64, false><<<NN / 16, 256, 0, stream>>>(hn, nullptr, nullptr, nullptr,
                                                   l0_Wl, l0_Wr, X, Y);
    k_gat<<<NGRAPH * 8, 256, 0, stream>>>(row_start, row_cnt, ssd, ea_s,
                                          l0_We, l0_att, l0_b, X, Y, V, stats0);

    // GAT layer 1 (BN+leaky of layer-0 output fused into projection load)
    k_xlxr<256, true><<<NN / 16, 256, 0, stream>>>(V, stats0, l0_bn_g, l0_bn_b,
                                                   l1_Wl, l1_Wr, X, Y);
    k_gat<<<NGRAPH * 8, 256, 0, stream>>>(row_start, row_cnt, ssd, ea_s,
                                          l1_We, l1_att, l1_b, X, Y, V, stats1);

    // BN+leaky of layer-1 output fused into pooling
    k_pool_fc<<<NGRAPH, 256, 0, stream>>>(V, stats1, l1_bn_g, l1_bn_b, fc2_W, fc2_b, out);
}